// Round 1
// baseline (2276.282 us; speedup 1.0000x reference)
//
#include <hip/hip_runtime.h>

// ---------------------------------------------------------------------------
// AttentionDecoder: B=64 T=32 S=64 H=1024 V=32000
// Design:
//  - Precompute encT = enc @ l1 (split-bf16 MFMA, one 128x128-tile GEMM).
//  - 32 sequential steps, 4 kernels each:
//      k_gemm64(GATES): split-K split-bf16 MFMA -> gi/gh partials
//      k_attn: finalize h (GRU), f32 scores vs encT, softmax+mask, ctx,
//              write cat=[ctx,h] hi/lo, attention weights, (t==31) hidden out
//      k_gemm64(L2): split-K split-bf16 MFMA -> ctx_new partials
//      k_ctxfin: reduce+tanh -> ctx_{t+1} hi/lo (hi doubles as big-GEMM A)
//  - Big GEMM (2048x32000,K=1024) bf16 MFMA + bias -> logits into d_out
//  - k_lsm: per-row online log-softmax in place.
// Split-bf16 (hi/lo) makes recurrence effectively f32-accurate (residual
// ~(0.4%)^2), needed because attention-weight threshold ~0.024.
// ---------------------------------------------------------------------------

#define B_ 64
#define T_ 32
#define S_ 64
#define H_ 1024
#define V_ 32000

#define HID_OFF 65536000L
#define ATT_OFF 65601536L
#define CTF_OFF 65732608L

typedef __attribute__((ext_vector_type(8))) short bf16x8;
typedef __attribute__((ext_vector_type(4))) float f32x4;
typedef __attribute__((ext_vector_type(4))) unsigned int u32x4;
typedef unsigned short u16;

__device__ __forceinline__ u16 f2bf(float v) {
  unsigned int u = __float_as_uint(v);
  unsigned int r = (u + 0x7fffu + ((u >> 16) & 1u)) >> 16;  // RNE
  return (u16)r;
}
__device__ __forceinline__ float bf2f(u16 h) {
  return __uint_as_float(((unsigned int)h) << 16);
}
__device__ __forceinline__ void split2(float v, u16* hi, u16* lo) {
  u16 h = f2bf(v);
  *hi = h;
  *lo = f2bf(v - bf2f(h));
}

// ---------------- conversion / prep kernels ----------------

__global__ void k_split(const float* __restrict__ src, u16* __restrict__ hi,
                        u16* __restrict__ lo, int n) {
  int i = blockIdx.x * blockDim.x + threadIdx.x;
  int stride = gridDim.x * blockDim.x;
  for (; i < n; i += stride) split2(src[i], &hi[i], &lo[i]);
}

__global__ void k_tobf(const float* __restrict__ src, u16* __restrict__ dst, int n) {
  int i = blockIdx.x * blockDim.x + threadIdx.x;
  int stride = gridDim.x * blockDim.x;
  for (; i < n; i += stride) dst[i] = f2bf(src[i]);
}

// l1 (H,H) row-major [i][k] -> l1T hi/lo [k][i]
__global__ void k_l1t(const float* __restrict__ l1, u16* __restrict__ hi,
                      u16* __restrict__ lo) {
  __shared__ float tile[64][65];
  int it = blockIdx.x & 15, kt = blockIdx.x >> 4;
  for (int q = 0; q < 16; ++q) {
    int idx = q * 256 + threadIdx.x;
    int r = idx >> 6, c = idx & 63;
    tile[r][c] = l1[(long)(it * 64 + r) * H_ + kt * 64 + c];
  }
  __syncthreads();
  for (int q = 0; q < 16; ++q) {
    int idx = q * 256 + threadIdx.x;
    int r = idx >> 6, c = idx & 63;
    long o = (long)(kt * 64 + r) * H_ + it * 64 + c;
    split2(tile[c][r], &hi[o], &lo[o]);
  }
}

// gather embeddings: embx[t][b][k] hi/lo
__global__ void k_embx(const int* __restrict__ inp, const float* __restrict__ emb,
                       u16* __restrict__ hi, u16* __restrict__ lo) {
  int bt = blockIdx.x;
  int b = bt >> 5, t = bt & 31;
  int id = inp[b * T_ + t];
  const float* src = emb + (long)id * H_;
  long base = (long)(t * B_ + b) * H_;
  for (int k = threadIdx.x; k < H_; k += 256) split2(src[k], &hi[base + k], &lo[base + k]);
}

__global__ void k_h0(const float* __restrict__ mem, float* __restrict__ hf,
                     u16* __restrict__ hh, u16* __restrict__ hl) {
  int i = blockIdx.x * 256 + threadIdx.x;  // 65536
  float v = mem[i];
  hf[i] = v;
  split2(v, &hh[i], &hl[i]);
}

__global__ void k_guard(float* out, float v) {
  if (blockIdx.x == 0 && threadIdx.x == 0) out[0] = v;
}

// ---------------- 128x128 tile GEMM (BK=32), optional split-bf16 ----------------
// A: (M,K) row-major bf16 (hi[,lo]); B: (N,K) row-major bf16 (hi[,lo])
// OMODE 0: C[(m0+r)*Crow + n0+c] = acc   (f32)
// OMODE 1: logits: C[((m&63)*T_ + (m>>6))*V_ + n] = acc + bias[n]
template <int SPLIT, int OMODE>
__launch_bounds__(256)
__global__ void k_gemm128(const u16* __restrict__ Ah, const u16* __restrict__ Al,
                          const u16* __restrict__ Bh, const u16* __restrict__ Bl,
                          float* __restrict__ C, const float* __restrict__ bias,
                          int Mtiles, int Ntiles, int K, int Arow, int Brow, int Crow) {
  (void)Ntiles;
  int bx = blockIdx.x;
  int mt = bx % Mtiles, nt = bx / Mtiles;
  int m0 = mt * 128, n0 = nt * 128;

  __shared__ __attribute__((aligned(16))) u16 lds[(SPLIT ? 4 : 2) * 4096];
  char* L = (char*)lds;
  const int tid = threadIdx.x;
  const int lane = tid & 63, wid = tid >> 6;
  const int wm = wid & 1, wn = wid >> 1;
  const int l15 = lane & 15, kq = lane >> 4;

  f32x4 acc[4][4];
  const f32x4 z4 = {0.f, 0.f, 0.f, 0.f};
#pragma unroll
  for (int i = 0; i < 4; ++i)
#pragma unroll
    for (int j = 0; j < 4; ++j) acc[i][j] = z4;

  const int ksteps = K >> 5;
  for (int kt = 0; kt < ksteps; ++kt) {
    __syncthreads();
#pragma unroll
    for (int h2 = 0; h2 < 2; ++h2) {
      int r = (tid >> 2) + (h2 << 6);
      int slot = tid & 3;
      int so = ((slot ^ (r & 3)) << 4);
      long ga = (long)(m0 + r) * Arow + (kt << 5) + (slot << 3);
      long gb = (long)(n0 + r) * Brow + (kt << 5) + (slot << 3);
      *(u32x4*)(L + r * 64 + so) = *(const u32x4*)(Ah + ga);
      *(u32x4*)(L + 8192 + r * 64 + so) = *(const u32x4*)(Bh + gb);
      if (SPLIT) {
        *(u32x4*)(L + 16384 + r * 64 + so) = *(const u32x4*)(Al + ga);
        *(u32x4*)(L + 24576 + r * 64 + so) = *(const u32x4*)(Bl + gb);
      }
    }
    __syncthreads();
    bf16x8 aH[4], bH[4], aL[4], bL[4];
#pragma unroll
    for (int mi = 0; mi < 4; ++mi) {
      int r = (wm << 6) + (mi << 4) + l15;
      int off = r * 64 + ((kq ^ (r & 3)) << 4);
      aH[mi] = *(const bf16x8*)(L + off);
      if (SPLIT) aL[mi] = *(const bf16x8*)(L + 16384 + off);
    }
#pragma unroll
    for (int ni = 0; ni < 4; ++ni) {
      int c = (wn << 6) + (ni << 4) + l15;
      int off = c * 64 + ((kq ^ (c & 3)) << 4);
      bH[ni] = *(const bf16x8*)(L + 8192 + off);
      if (SPLIT) bL[ni] = *(const bf16x8*)(L + 24576 + off);
    }
#pragma unroll
    for (int mi = 0; mi < 4; ++mi)
#pragma unroll
      for (int ni = 0; ni < 4; ++ni) {
        acc[mi][ni] = __builtin_amdgcn_mfma_f32_16x16x32_bf16(aH[mi], bH[ni], acc[mi][ni], 0, 0, 0);
        if (SPLIT) {
          acc[mi][ni] = __builtin_amdgcn_mfma_f32_16x16x32_bf16(aL[mi], bH[ni], acc[mi][ni], 0, 0, 0);
          acc[mi][ni] = __builtin_amdgcn_mfma_f32_16x16x32_bf16(aH[mi], bL[ni], acc[mi][ni], 0, 0, 0);
        }
      }
  }
#pragma unroll
  for (int mi = 0; mi < 4; ++mi)
#pragma unroll
    for (int ni = 0; ni < 4; ++ni)
#pragma unroll
      for (int e = 0; e < 4; ++e) {
        int r = (wm << 6) + (mi << 4) + (kq << 2) + e;
        int c = (wn << 6) + (ni << 4) + l15;
        int gm = m0 + r, gn = n0 + c;
        float v = acc[mi][ni][e];
        if (OMODE == 0) {
          C[(long)gm * Crow + gn] = v;
        } else {
          v += bias[gn];
          C[((long)(gm & 63) * T_ + (gm >> 6)) * V_ + gn] = v;
        }
      }
}

// ---------------- 64x64 tile split-bf16 GEMM, K=512 chunk, partial writer ----
// mode 0 (GATES): blocks [0,192): gi (x @ w_ih^T), [192,288): gh (h @ w_hh^T)
// mode 1 (L2):    64 blocks: cat @ l2^T -> ctxp partials
__launch_bounds__(256)
__global__ void k_gemm64(int mode, int t,
                         const u16* __restrict__ embx_h, const u16* __restrict__ embx_l,
                         const u16* __restrict__ ctx_h, const u16* __restrict__ ctx_l,
                         const u16* __restrict__ h_h, const u16* __restrict__ h_l,
                         const u16* __restrict__ wih_h, const u16* __restrict__ wih_l,
                         const u16* __restrict__ whh_h, const u16* __restrict__ whh_l,
                         const u16* __restrict__ cat_h, const u16* __restrict__ cat_l,
                         const u16* __restrict__ l2_h, const u16* __restrict__ l2_l,
                         float* __restrict__ gip, float* __restrict__ ghp,
                         float* __restrict__ ctxp) {
  const u16 *Ah, *Al, *Bh, *Bl;
  float* outp;
  int Ar, Br, ostr;
  int bx = blockIdx.x;
  if (mode == 0) {
    if (bx < 192) {
      int nt = bx % 48, kc = bx / 48;
      if (kc < 2) {
        Ah = embx_h + (long)t * 65536 + kc * 512;
        Al = embx_l + (long)t * 65536 + kc * 512;
      } else {
        Ah = ctx_h + (long)t * 65536 + (kc - 2) * 512;
        Al = ctx_l + (long)t * 65536 + (kc - 2) * 512;
      }
      Ar = 1024;
      Bh = wih_h + (long)nt * 64 * 2048 + kc * 512;
      Bl = wih_l + (long)nt * 64 * 2048 + kc * 512;
      Br = 2048;
      outp = gip + (long)kc * 196608 + nt * 64;
      ostr = 3072;
    } else {
      int b2 = bx - 192;
      int nt = b2 % 48, kc = b2 / 48;
      Ah = h_h + kc * 512;
      Al = h_l + kc * 512;
      Ar = 1024;
      Bh = whh_h + (long)nt * 64 * 1024 + kc * 512;
      Bl = whh_l + (long)nt * 64 * 1024 + kc * 512;
      Br = 1024;
      outp = ghp + (long)kc * 196608 + nt * 64;
      ostr = 3072;
    }
  } else {
    int nt = bx % 16, kc = bx / 16;
    Ah = cat_h + kc * 512;
    Al = cat_l + kc * 512;
    Ar = 2048;
    Bh = l2_h + (long)nt * 64 * 2048 + kc * 512;
    Bl = l2_l + (long)nt * 64 * 2048 + kc * 512;
    Br = 2048;
    outp = ctxp + (long)kc * 65536 + nt * 64;
    ostr = 1024;
  }

  __shared__ __attribute__((aligned(16))) u16 lds[4 * 2048];  // 16 KB
  char* L = (char*)lds;
  const int tid = threadIdx.x;
  const int lane = tid & 63, wid = tid >> 6;
  const int wm = wid & 1, wn = wid >> 1;
  const int l15 = lane & 15, kq = lane >> 4;

  f32x4 acc[2][2];
  const f32x4 z4 = {0.f, 0.f, 0.f, 0.f};
#pragma unroll
  for (int i = 0; i < 2; ++i)
#pragma unroll
    for (int j = 0; j < 2; ++j) acc[i][j] = z4;

  for (int kt = 0; kt < 16; ++kt) {
    __syncthreads();
    {
      int r = tid >> 2, slot = tid & 3;
      int so = ((slot ^ (r & 3)) << 4);
      long ga = (long)r * Ar + (kt << 5) + (slot << 3);
      long gb = (long)r * Br + (kt << 5) + (slot << 3);
      *(u32x4*)(L + r * 64 + so) = *(const u32x4*)(Ah + ga);
      *(u32x4*)(L + 4096 + r * 64 + so) = *(const u32x4*)(Bh + gb);
      *(u32x4*)(L + 8192 + r * 64 + so) = *(const u32x4*)(Al + ga);
      *(u32x4*)(L + 12288 + r * 64 + so) = *(const u32x4*)(Bl + gb);
    }
    __syncthreads();
    bf16x8 aH[2], aL[2], bH[2], bL[2];
#pragma unroll
    for (int mi = 0; mi < 2; ++mi) {
      int r = (wm << 5) + (mi << 4) + l15;
      int off = r * 64 + ((kq ^ (r & 3)) << 4);
      aH[mi] = *(const bf16x8*)(L + off);
      aL[mi] = *(const bf16x8*)(L + 8192 + off);
    }
#pragma unroll
    for (int ni = 0; ni < 2; ++ni) {
      int c = (wn << 5) + (ni << 4) + l15;
      int off = c * 64 + ((kq ^ (c & 3)) << 4);
      bH[ni] = *(const bf16x8*)(L + 4096 + off);
      bL[ni] = *(const bf16x8*)(L + 12288 + off);
    }
#pragma unroll
    for (int mi = 0; mi < 2; ++mi)
#pragma unroll
      for (int ni = 0; ni < 2; ++ni) {
        acc[mi][ni] = __builtin_amdgcn_mfma_f32_16x16x32_bf16(aH[mi], bH[ni], acc[mi][ni], 0, 0, 0);
        acc[mi][ni] = __builtin_amdgcn_mfma_f32_16x16x32_bf16(aL[mi], bH[ni], acc[mi][ni], 0, 0, 0);
        acc[mi][ni] = __builtin_amdgcn_mfma_f32_16x16x32_bf16(aH[mi], bL[ni], acc[mi][ni], 0, 0, 0);
      }
  }
#pragma unroll
  for (int mi = 0; mi < 2; ++mi)
#pragma unroll
    for (int ni = 0; ni < 2; ++ni)
#pragma unroll
      for (int e = 0; e < 4; ++e) {
        int b = (wm << 5) + (mi << 4) + (kq << 2) + e;
        int c = (wn << 5) + (ni << 4) + l15;
        outp[(long)b * ostr + c] = acc[mi][ni][e];
      }
}

// ---------------- per-step attention / GRU finalize ----------------
__launch_bounds__(256)
__global__ void k_attn(int t, const float* __restrict__ gip, const float* __restrict__ ghp,
                       const float* __restrict__ bih, const float* __restrict__ bhh,
                       float* __restrict__ hf, u16* __restrict__ hh, u16* __restrict__ hl,
                       const float* __restrict__ encT, const float* __restrict__ enc,
                       const int* __restrict__ xs_len,
                       u16* __restrict__ cat_h, u16* __restrict__ cat_l,
                       float* __restrict__ dout) {
  int b = blockIdx.x;
  int tid = threadIdx.x;
  __shared__ __attribute__((aligned(16))) float hs[1024];
  __shared__ float sc_s[64];
  __shared__ float at_s[64];

  // GRU finalize: h_new[b][j]
  for (int j = tid; j < 1024; j += 256) {
    float ir = 0.f, iz = 0.f, inn = 0.f;
#pragma unroll
    for (int kc = 0; kc < 4; ++kc) {
      const float* g = gip + (long)kc * 196608 + b * 3072;
      ir += g[j];
      iz += g[1024 + j];
      inn += g[2048 + j];
    }
    float hr = 0.f, hz = 0.f, hn = 0.f;
#pragma unroll
    for (int kc = 0; kc < 2; ++kc) {
      const float* g = ghp + (long)kc * 196608 + b * 3072;
      hr += g[j];
      hz += g[1024 + j];
      hn += g[2048 + j];
    }
    ir += bih[j]; iz += bih[1024 + j]; inn += bih[2048 + j];
    hr += bhh[j]; hz += bhh[1024 + j]; hn += bhh[2048 + j];
    float r = 1.f / (1.f + expf(-(ir + hr)));
    float z = 1.f / (1.f + expf(-(iz + hz)));
    float n = tanhf(inn + r * hn);
    float hp = hf[b * 1024 + j];
    float h = (1.f - z) * n + z * hp;
    hs[j] = h;
    hf[b * 1024 + j] = h;
    split2(h, &hh[b * 1024 + j], &hl[b * 1024 + j]);
  }
  __syncthreads();

  // scores: 4 threads per s
  {
    int s = tid >> 2, part = tid & 3;
    const float4* er = (const float4*)(encT + ((long)b * 64 + s) * 1024);
    const float4* hv = (const float4*)hs;
    float dot = 0.f;
    for (int q = part; q < 256; q += 4) {
      float4 e = er[q], h4 = hv[q];
      dot += e.x * h4.x + e.y * h4.y + e.z * h4.z + e.w * h4.w;
    }
    dot += __shfl_xor(dot, 1);
    dot += __shfl_xor(dot, 2);
    if (part == 0) sc_s[s] = dot;
  }
  __syncthreads();

  if (tid < 64) {
    int len = xs_len[b];
    float v = sc_s[tid];
    if (tid >= len || v == 0.0f) v = -1e10f;  // ref: mask*score==0 -> -1e10
    float m = v;
#pragma unroll
    for (int off = 32; off; off >>= 1) m = fmaxf(m, __shfl_xor(m, off));
    float p = expf(v - m);
    float sum = p;
#pragma unroll
    for (int off = 32; off; off >>= 1) sum += __shfl_xor(sum, off);
    float a = p / sum;
    at_s[tid] = a;
    dout[ATT_OFF + ((long)b * T_ + t) * S_ + tid] = a;
  }
  __syncthreads();

  // ctx = attn @ enc[b]; write cat=[ctx,h] hi/lo
  {
    const float4* encb = (const float4*)(enc + (long)b * 64 * 1024);
    float c0 = 0.f, c1 = 0.f, c2 = 0.f, c3 = 0.f;
    for (int s2 = 0; s2 < 64; ++s2) {
      float a = at_s[s2];
      float4 e4 = encb[s2 * 256 + tid];
      c0 += a * e4.x; c1 += a * e4.y; c2 += a * e4.z; c3 += a * e4.w;
    }
    int k0 = tid * 4;
    float cv[4] = {c0, c1, c2, c3};
#pragma unroll
    for (int ii = 0; ii < 4; ++ii) {
      split2(cv[ii], &cat_h[b * 2048 + k0 + ii], &cat_l[b * 2048 + k0 + ii]);
      float h = hs[k0 + ii];
      split2(h, &cat_h[b * 2048 + 1024 + k0 + ii], &cat_l[b * 2048 + 1024 + k0 + ii]);
      if (t == T_ - 1) dout[HID_OFF + (long)b * 1024 + k0 + ii] = h;
    }
  }
}

// ---------------- ctx_new finalize ----------------
__global__ void k_ctxfin(int t, const float* __restrict__ ctxp, u16* __restrict__ ctx_h,
                         u16* __restrict__ ctx_l, float* __restrict__ dout) {
  int i = blockIdx.x * 256 + threadIdx.x;  // 65536
  float p = ctxp[i] + ctxp[65536 + i] + ctxp[2 * 65536 + i] + ctxp[3 * 65536 + i];
  float v = tanhf(p);
  long o = (long)(t + 1) * 65536 + i;
  split2(v, &ctx_h[o], &ctx_l[o]);  // ctx_h slots 1..32 are also the big-GEMM A
  if (t == T_ - 1) dout[CTF_OFF + i] = v;
}

// ---------------- in-place log-softmax over V per row ----------------
__device__ __forceinline__ void lse_comb(float& m, float& s, float mo, float so) {
  float M = fmaxf(m, mo);
  s = s * __expf(m - M) + so * __expf(mo - M);
  m = M;
}

__launch_bounds__(256)
__global__ void k_lsm(float* __restrict__ dout) {
  long base = (long)blockIdx.x * V_;
  int tid = threadIdx.x;
  float m = -3.0e38f, s = 0.f;
  for (int v = tid; v < V_; v += 256) {
    float x = dout[base + v];
    if (x > m) {
      s = s * __expf(m - x) + 1.f;
      m = x;
    } else {
      s += __expf(x - m);
    }
  }
#pragma unroll
  for (int off = 32; off; off >>= 1) {
    float mo = __shfl_xor(m, off), so = __shfl_xor(s, off);
    lse_comb(m, s, mo, so);
  }
  __shared__ float ms[4], ss[4];
  if ((tid & 63) == 0) { ms[tid >> 6] = m; ss[tid >> 6] = s; }
  __syncthreads();
  float M = ms[0], S = ss[0];
  for (int w2 = 1; w2 < 4; ++w2) lse_comb(M, S, ms[w2], ss[w2]);
  float logden = M + logf(S);
  for (int v = tid; v < V_; v += 256) dout[base + v] -= logden;
}

// ---------------- host launcher ----------------
extern "C" void kernel_launch(void* const* d_in, const int* in_sizes, int n_in,
                              void* d_out, int out_size, void* d_ws, size_t ws_size,
                              hipStream_t stream) {
  (void)in_sizes; (void)n_in; (void)out_size;
  const int* input = (const int*)d_in[0];
  const float* memory = (const float*)d_in[1];
  const float* enc = (const float*)d_in[2];
  const int* xs_len = (const int*)d_in[3];
  const float* emb = (const float*)d_in[4];
  const float* wih = (const float*)d_in[5];
  const float* whh = (const float*)d_in[6];
  const float* bih = (const float*)d_in[7];
  const float* bhh = (const float*)d_in[8];
  const float* l1 = (const float*)d_in[9];
  const float* l2 = (const float*)d_in[10];
  const float* wout = (const float*)d_in[11];
  const float* bout = (const float*)d_in[12];
  float* out = (float*)d_out;
  char* w = (char*)d_ws;

  size_t off = 0;
  auto alloc = [&](size_t bytes) {
    size_t o = off;
    off = (off + bytes + 255) & ~(size_t)255;
    return o;
  };
  const size_t N_WIH = 3072UL * 2048, N_WHH = 3072UL * 1024, N_L2 = 1024UL * 2048;
  const size_t N_L1 = 1024UL * 1024, N_ENC = 4096UL * 1024, N_WOUT = 32000UL * 1024;
  const size_t N_EMBX = 2048UL * 1024, N_ENCT = 4096UL * 1024, N_CTX = 33UL * 65536;

  size_t o_wih_h = alloc(2 * N_WIH), o_wih_l = alloc(2 * N_WIH);
  size_t o_whh_h = alloc(2 * N_WHH), o_whh_l = alloc(2 * N_WHH);
  size_t o_l2_h = alloc(2 * N_L2), o_l2_l = alloc(2 * N_L2);
  size_t o_l1t_h = alloc(2 * N_L1), o_l1t_l = alloc(2 * N_L1);
  size_t o_enc_h = alloc(2 * N_ENC), o_enc_l = alloc(2 * N_ENC);
  size_t o_wout = alloc(2 * N_WOUT);
  size_t o_embx_h = alloc(2 * N_EMBX), o_embx_l = alloc(2 * N_EMBX);
  size_t o_encT = alloc(4 * N_ENCT);
  size_t o_ctx_h = alloc(2 * N_CTX), o_ctx_l = alloc(2 * N_CTX);
  size_t o_hf = alloc(4 * 65536), o_hh = alloc(2 * 65536), o_hl = alloc(2 * 65536);
  size_t o_cat_h = alloc(2 * 131072), o_cat_l = alloc(2 * 131072);
  size_t o_gip = alloc(4 * 786432), o_ghp = alloc(4 * 393216), o_ctxp = alloc(4 * 262144);

  if (off > ws_size) {
    k_guard<<<1, 1, 0, stream>>>(out, 1.0e8f + (float)(ws_size >> 20));
    return;
  }

  u16* wih_h = (u16*)(w + o_wih_h);   u16* wih_l = (u16*)(w + o_wih_l);
  u16* whh_h = (u16*)(w + o_whh_h);   u16* whh_l = (u16*)(w + o_whh_l);
  u16* l2_h = (u16*)(w + o_l2_h);     u16* l2_l = (u16*)(w + o_l2_l);
  u16* l1t_h = (u16*)(w + o_l1t_h);   u16* l1t_l = (u16*)(w + o_l1t_l);
  u16* enc_h = (u16*)(w + o_enc_h);   u16* enc_l = (u16*)(w + o_enc_l);
  u16* wout_b = (u16*)(w + o_wout);
  u16* embx_h = (u16*)(w + o_embx_h); u16* embx_l = (u16*)(w + o_embx_l);
  float* encT = (float*)(w + o_encT);
  u16* ctx_h = (u16*)(w + o_ctx_h);   u16* ctx_l = (u16*)(w + o_ctx_l);
  float* hf = (float*)(w + o_hf);
  u16* hh = (u16*)(w + o_hh);         u16* hl = (u16*)(w + o_hl);
  u16* cat_h = (u16*)(w + o_cat_h);   u16* cat_l = (u16*)(w + o_cat_l);
  float* gip = (float*)(w + o_gip);
  float* ghp = (float*)(w + o_ghp);
  float* ctxp = (float*)(w + o_ctxp);

  // prep
  k_split<<<2048, 256, 0, stream>>>(wih, wih_h, wih_l, (int)N_WIH);
  k_split<<<2048, 256, 0, stream>>>(whh, whh_h, whh_l, (int)N_WHH);
  k_split<<<2048, 256, 0, stream>>>(l2, l2_h, l2_l, (int)N_L2);
  k_split<<<2048, 256, 0, stream>>>(enc, enc_h, enc_l, (int)N_ENC);
  k_l1t<<<256, 256, 0, stream>>>(l1, l1t_h, l1t_l);
  k_tobf<<<4096, 256, 0, stream>>>(wout, wout_b, (int)N_WOUT);
  k_embx<<<2048, 256, 0, stream>>>(input, emb, embx_h, embx_l);
  k_h0<<<256, 256, 0, stream>>>(memory, hf, hh, hl);
  hipMemsetAsync(ctx_h, 0, 131072, stream);  // ctx slot 0 = zeros
  hipMemsetAsync(ctx_l, 0, 131072, stream);

  // encT = enc @ l1  (split-bf16)
  k_gemm128<1, 0><<<256, 256, 0, stream>>>(enc_h, enc_l, l1t_h, l1t_l, encT, nullptr,
                                           32, 8, 1024, 1024, 1024, 1024);

  for (int t = 0; t < T_; ++t) {
    k_gemm64<<<288, 256, 0, stream>>>(0, t, embx_h, embx_l, ctx_h, ctx_l, hh, hl,
                                      wih_h, wih_l, whh_h, whh_l, cat_h, cat_l,
                                      l2_h, l2_l, gip, ghp, ctxp);
    k_attn<<<64, 256, 0, stream>>>(t, gip, ghp, bih, bhh, hf, hh, hl, encT, enc,
                                   xs_len, cat_h, cat_l, out);
    k_gemm64<<<64, 256, 0, stream>>>(1, t, embx_h, embx_l, ctx_h, ctx_l, hh, hl,
                                     wih_h, wih_l, whh_h, whh_l, cat_h, cat_l,
                                     l2_h, l2_l, gip, ghp, ctxp);
    k_ctxfin<<<256, 256, 0, stream>>>(t, ctxp, ctx_h, ctx_l, out);
  }

  // logits = ctx_all @ w_out^T + b_out, scattered to [b][t][v]
  k_gemm128<0, 1><<<4000, 256, 0, stream>>>(ctx_h + 65536, nullptr, wout_b, nullptr,
                                            out, bout, 16, 250, 1024, 1024, 1024, 0);
  // in-place log-softmax per (b,t) row
  k_lsm<<<2048, 256, 0, stream>>>(out);
}